// Round 6
// baseline (106.423 us; speedup 1.0000x reference)
//
#include <hip/hip_runtime.h>

// SiamFC cross-correlation: out[n,0,oh,ow] = sum_{c,i,j} x[n,c,oh+i,ow+j] * z[n,c,i,j]
// n=256, c=256, z=6x6, x=26x26, out=21x21.
//
// Block = 128 threads (2 waves): lane -> cc = tid&7 (channel), t = (tid>>3)&7
// (row-tile, 7 valid: output rows 3t..3t+2), h = tid>>6 (z-row half 3h..3h+2).
// Per thread: 5 x-rows x 7 ds_read_b128 = 35 reads for 1134 FMAs (32:1).
// Bank groups: (k - m - 3t - 3h - 183*cc) mod 8, 183 odd -> cc sweeps all 8
// groups per t-stripe -> conflict-free by construction.
// Grid = 256 samples x 32 splits (8 ch each), single staging round.
//
// ROUND-5 BUG FIX: z staging was `if (tid < 144)` with only 128 threads ->
// channel 7's z[4..35] never staged (garbage LDS). Now a strided loop.

#define C_ALL 256
#define HZ 6
#define WZ 6
#define HX 26
#define WX 26
#define OH 21
#define OW 21
#define PADW 28
#define CHS 732                 // x channel stride in LDS floats (183*4, 183 odd mod 8)
#define ZSTR 38                 // z channel stride (8 disjoint bank pairs across cc)
#define CCON 8
#define SPLITS 32
#define NTHREADS 128
#define SLOT_STRIDE 68          // partial-slot stride: 17*s mod 8 = s mod 8 -> spread
#define LDSW 7616               // max(8*732+8*38 = 6160, 112*68 = 7616)

__global__ __launch_bounds__(NTHREADS, 2)
void siamfc_xcorr(const float* __restrict__ z, const float* __restrict__ x,
                  float* __restrict__ out) {
    __shared__ __align__(16) float lds[LDSW];
    float* xs = lds;            // 8 * 732
    float* zs = lds + CCON * CHS;

    const int tid = threadIdx.x;
    const int bid = blockIdx.x;
    const int n     = bid >> 5;
    const int split = bid & 31;
    const int cbase = split * CCON;

    const int cc = tid & 7;
    const int t  = (tid >> 3) & 7;     // 0..7, t=7 idle in compute
    const int h  = tid >> 6;           // wave0: h=0, wave1: h=1
    const bool active = (t < 7);

    // ---- stage x: 8 ch x 338 float2 (coalesced), rows padded 26->28
    {
        const float2* xg = (const float2*)(x + (size_t)n * C_ALL * (HX * WX))
                           + (size_t)cbase * (HX * WX / 2);
        for (int u = tid; u < CCON * (HX * WX / 2); u += NTHREADS) {
            float2 v = xg[u];
            int ch  = u / 338;
            int rm  = u - ch * 338;
            int row = rm / 13;
            int seg = rm - row * 13;
            *(float2*)&xs[ch * CHS + row * PADW + 2 * seg] = v;
        }
        // ---- stage z: 8 ch x 18 float2 (STRIDED: 144 elements > 128 threads)
        const float2* zg = (const float2*)(z + (size_t)n * C_ALL * (HZ * WZ))
                           + (size_t)cbase * (HZ * WZ / 2);
        for (int u = tid; u < CCON * (HZ * WZ / 2); u += NTHREADS) {
            float2 v = zg[u];
            int ch = u / 18;
            int rm = u - ch * 18;
            *(float2*)&zs[ch * ZSTR + 2 * rm] = v;
        }
    }
    __syncthreads();

    float acc[3 * OW];
    #pragma unroll
    for (int o = 0; o < 3 * OW; ++o) acc[o] = 0.f;

    if (active) {
        // z rows 3h..3h+2 into registers (9 conflict-free b64 broadcasts)
        float zv[3][WZ];
        const float2* zp = (const float2*)&zs[cc * ZSTR + 18 * h];
        #pragma unroll
        for (int e = 0; e < 9; ++e) {
            float2 w = zp[e];
            zv[e / 3][(e % 3) * 2]     = w.x;
            zv[e / 3][(e % 3) * 2 + 1] = w.y;
        }
        const float* xc = xs + cc * CHS + (3 * t + 3 * h) * PADW;
        #pragma unroll
        for (int m = 0; m < 5; ++m) {      // x rows 3t+3h+m, each read once
            float xr[PADW];
            const float4* rp = (const float4*)(xc + m * PADW);
            #pragma unroll
            for (int k = 0; k < 7; ++k) {
                float4 f = rp[k];
                xr[4*k+0] = f.x; xr[4*k+1] = f.y;
                xr[4*k+2] = f.z; xr[4*k+3] = f.w;
            }
            // valid (zr, a=m-zr) pairs, all indices compile-time
            #pragma unroll
            for (int zr = 0; zr < 3; ++zr) {
                const int a = m - zr;
                if (a >= 0 && a < 3) {
                    #pragma unroll
                    for (int j = 0; j < WZ; ++j)
                        #pragma unroll
                        for (int o = 0; o < OW; ++o)
                            acc[a * OW + o] = fmaf(zv[zr][j], xr[o + j], acc[a * OW + o]);
                }
            }
        }
    }
    __syncthreads();    // compute done; reuse lds for partials

    // ---- write 63 partials per active thread, slot stride 68 (aligned b128)
    if (active) {
        const int s = h * 56 + t * 8 + cc;
        float* w = &lds[s * SLOT_STRIDE];
        #pragma unroll
        for (int v = 0; v < 15; ++v) {
            float4 f = { acc[4*v+0], acc[4*v+1], acc[4*v+2], acc[4*v+3] };
            *(float4*)&w[4 * v] = f;
        }
        w[60] = acc[60]; w[61] = acc[61]; w[62] = acc[62];
    }
    __syncthreads();

    // ---- fold 16 slots (8 cc x 2 h) per output, one atomic per output per block
    float* og = out + (size_t)n * (OH * OW);
    for (int o = tid; o < OH * OW; o += NTHREADS) {
        int row = o / OW, col = o - row * OW;
        int tt = row / 3, a = row - tt * 3;
        int vi = a * OW + col;
        float sum = 0.f;
        #pragma unroll
        for (int hh = 0; hh < 2; ++hh)
            #pragma unroll
            for (int c2 = 0; c2 < 8; ++c2)
                sum += lds[(hh * 56 + tt * 8 + c2) * SLOT_STRIDE + vi];
        atomicAdd(&og[o], sum);
    }
}

extern "C" void kernel_launch(void* const* d_in, const int* in_sizes, int n_in,
                              void* d_out, int out_size, void* d_ws, size_t ws_size,
                              hipStream_t stream) {
    const float* z = (const float*)d_in[0];
    const float* x = (const float*)d_in[1];
    float* out = (float*)d_out;
    hipMemsetAsync(d_out, 0, (size_t)out_size * sizeof(float), stream);
    siamfc_xcorr<<<dim3(256 * SPLITS), dim3(NTHREADS), 0, stream>>>(z, x, out);
}

// Round 7
// 62.083 us; speedup vs baseline: 1.7142x; 1.7142x over previous
//
#include <hip/hip_runtime.h>

// SiamFC cross-correlation: out[n,0,oh,ow] = sum_{c,i,j} x[n,c,oh+i,ow+j] * z[n,c,i,j]
// n=256, c=256, z=6x6, x=26x26, out=21x21.
//
// Round-7: memory-latency fix. global_load_lds (16B) staging direct to LDS,
// double-buffered, counted s_waitcnt vmcnt(7) + raw s_barrier so next round's
// HBM loads fly under current round's FMA phase. 8 rounds x 4 channels/block.
// Lanes: cc=tid&3 (channel), g=(tid>>2)&1 (col half), t=(tid>>3)&7 (3-row tile,
// 7 used), h=wave (z rows 3h..3h+2). 594 FMA per 49 ds_read_b64 per round.
// Epilogue: shfl_xor over cc, LDS fold over h, 441 atomicAdd per block.

#define HX 26
#define WX 26
#define OH 21
#define OW 21
#define XBUF 2704              // 4 ch * 676 floats
#define ZBUF 144               // 4 ch * 36 floats
#define BUFSTRIDE 2848         // XBUF + ZBUF (floats, 16B multiple)
#define NTHREADS 128
#define ROUNDS 8
#define SPLITS 8
#define SLOT 36                // partial slot stride (floats)

typedef __attribute__((address_space(3))) unsigned int lds_u32_t;
typedef __attribute__((address_space(1))) const unsigned int glb_u32_t;

__device__ __forceinline__ void gload16(const void* g, void* l) {
    __builtin_amdgcn_global_load_lds((glb_u32_t*)g, (lds_u32_t*)l, 16, 0, 0);
}

__global__ __launch_bounds__(NTHREADS, 3)
void siamfc_xcorr(const float* __restrict__ z, const float* __restrict__ x,
                  float* __restrict__ out) {
    __shared__ __align__(16) float lds[2 * BUFSTRIDE];

    const int tid  = threadIdx.x;
    const int lane = tid & 63;
    const int w    = tid >> 6;          // wave id == h
    const int bid  = blockIdx.x;
    const int n     = bid >> 3;
    const int split = bid & 7;
    const int cb0   = split * 32;       // 32 channels per block

    const int cc = tid & 3;
    const int g  = (tid >> 2) & 1;      // col half: cols 10g + o (g=1: o>=1)
    const int t  = (tid >> 3) & 7;      // 0..7, t==7 idle in compute
    const int h  = w;
    const bool active = (t < 7);

    const float4* xg4 = (const float4*)x + (size_t)n * (256 * 169);
    const float4* zg4 = (const float4*)z + (size_t)n * (256 * 9);

    // issue the 7 per-wave global_load_lds for round r into buffer b
    auto issue = [&](int r, int b) {
        const float4* xsrc = xg4 + (size_t)(cb0 + 4 * r) * 169;  // 676 quads
        const float4* zsrc = zg4 + (size_t)(cb0 + 4 * r) * 9;    // 36 quads
        float* xb = lds + b * BUFSTRIDE;
        float* zb = xb + XBUF;
        #pragma unroll
        for (int k = 0; k < 5; ++k)                      // quads k*128 + tid
            gload16(xsrc + k * 128 + tid, xb + (size_t)(k * 128 + w * 64) * 4);
        if (lane < 18)                                   // x quads 640..675
            gload16(xsrc + 640 + w * 18 + lane, xb + (size_t)(640 + w * 18) * 4);
        if (lane < 18)                                   // z quads 0..35
            gload16(zsrc + w * 18 + lane, zb + (size_t)(w * 18) * 4);
    };

    float acc[33];
    #pragma unroll
    for (int v = 0; v < 33; ++v) acc[v] = 0.f;

    issue(0, 0);

    #pragma unroll 1
    for (int r = 0; r < ROUNDS; ++r) {
        if (r < ROUNDS - 1) {
            issue(r + 1, (r + 1) & 1);
            asm volatile("s_waitcnt vmcnt(7)" ::: "memory");  // round-r loads done
        } else {
            asm volatile("s_waitcnt vmcnt(0)" ::: "memory");
        }
        __builtin_amdgcn_s_barrier();
        asm volatile("" ::: "memory");

        if (active) {
            const float* xb = lds + (r & 1) * BUFSTRIDE;
            const float* zb = xb + XBUF;
            // z rows 3h..3h+2 of channel cc: 9 float2 broadcasts
            float zv[3][6];
            const float2* zp = (const float2*)(zb + cc * 36 + h * 18);
            #pragma unroll
            for (int e = 0; e < 9; ++e) {
                float2 q = zp[e];
                zv[e / 3][2 * (e % 3)]     = q.x;
                zv[e / 3][2 * (e % 3) + 1] = q.y;
            }
            const float* xcb = xb + cc * 676;
            #pragma unroll
            for (int m = 0; m < 5; ++m) {                // x rows 3t+3h+m
                const int row = 3 * t + 3 * h + m;       // <= 25
                const float2* rp = (const float2*)xcb + 13 * row + 5 * g;
                float xr[16];                            // row floats 10g..10g+15
                #pragma unroll
                for (int s = 0; s < 8; ++s) {
                    float2 q = rp[s];
                    xr[2 * s] = q.x; xr[2 * s + 1] = q.y;
                }
                #pragma unroll
                for (int zr = 0; zr < 3; ++zr) {
                    const int a = m - zr;                // output row 3t+a
                    if (a >= 0 && a < 3) {
                        #pragma unroll
                        for (int j = 0; j < 6; ++j)
                            #pragma unroll
                            for (int o = 0; o < 11; ++o) // out col 10g+o
                                acc[a * 11 + o] = fmaf(zv[zr][j], xr[o + j], acc[a * 11 + o]);
                    }
                }
            }
        }
        __builtin_amdgcn_s_barrier();
        asm volatile("" ::: "memory");
    }

    // ---- reduce: shfl_xor across cc (lane bits 0,1), LDS slots across h
    #pragma unroll
    for (int v = 0; v < 33; ++v) {
        acc[v] += __shfl_xor(acc[v], 1, 64);
        acc[v] += __shfl_xor(acc[v], 2, 64);
    }
    if (active && cc == 0) {
        float* wsl = lds + (size_t)(h * 14 + t * 2 + g) * SLOT;
        #pragma unroll
        for (int v = 0; v < 33; ++v) wsl[v] = acc[v];
    }
    __syncthreads();

    float* og = out + (size_t)n * (OH * OW);
    for (int o = tid; o < OH * OW; o += NTHREADS) {
        int row = o / OW, c = o - row * OW;
        int tt = row / 3, a = row - tt * 3;
        int gg = (c >= 11) ? 1 : 0;
        int vi = a * 11 + (c - 10 * gg);
        float s = lds[(      tt * 2 + gg) * SLOT + vi]
                + lds[(14 +  tt * 2 + gg) * SLOT + vi];
        atomicAdd(&og[o], s);
    }
}

extern "C" void kernel_launch(void* const* d_in, const int* in_sizes, int n_in,
                              void* d_out, int out_size, void* d_ws, size_t ws_size,
                              hipStream_t stream) {
    const float* z = (const float*)d_in[0];
    const float* x = (const float*)d_in[1];
    float* out = (float*)d_out;
    hipMemsetAsync(d_out, 0, (size_t)out_size * sizeof(float), stream);
    siamfc_xcorr<<<dim3(256 * SPLITS), dim3(NTHREADS), 0, stream>>>(z, x, out);
}